// Round 1
// baseline (367.432 us; speedup 1.0000x reference)
//
#include <hip/hip_runtime.h>
#include <math.h>

#define S_LEN 1024
#define BATCH 8
#define NH 8
#define QD 32
#define PD 4
#define EMB 512
#define NPROJ 544
#define LPOS 2047  // 2*S-1

typedef __attribute__((ext_vector_type(8))) short short8;   // 8 bf16 = 4 VGPR
typedef __attribute__((ext_vector_type(4))) float f32x4;
typedef __attribute__((ext_vector_type(4))) unsigned int u32x4;
typedef __attribute__((ext_vector_type(2))) unsigned int u32x2;

union U4 { u32x4 u; short8 s; };

// fp32 -> bf16 round-to-nearest-even
static __device__ inline unsigned short f2bf(float f) {
    unsigned int u = __builtin_bit_cast(unsigned int, f);
    u += 0x7fffu + ((u >> 16) & 1u);
    return (unsigned short)(u >> 16);
}

// ---------------------------------------------------------------------------
// Kernel 0 (merged): blocks [0,4368) convert X/W f32->bf16;
//                    blocks [4368,4624) compute PE and store reversed bf16.
// ---------------------------------------------------------------------------
#define NXV 1048576   // X float4 count
#define NWV 69632     // W float4 count
#define CONV_BLOCKS 4368
__global__ __launch_bounds__(256) void prep_kernel(
    const float* __restrict__ X, const float* __restrict__ W,
    const float* __restrict__ pos, const float* __restrict__ Wp,
    unsigned short* __restrict__ Xb, unsigned short* __restrict__ Wb,
    unsigned short* __restrict__ PEr)
{
    const int bx = blockIdx.x;
    if (bx < CONV_BLOCKS) {
        int idx = bx * 256 + threadIdx.x;
        const f32x4* src;
        unsigned short* dst;
        int i;
        if (idx < NXV)            { src = (const f32x4*)X; dst = Xb; i = idx; }
        else if (idx < NXV + NWV) { src = (const f32x4*)W; dst = Wb; i = idx - NXV; }
        else return;
        f32x4 v = src[i];
        union { unsigned short s[4]; u32x2 u; } pk;
        pk.s[0] = f2bf(v.x); pk.s[1] = f2bf(v.y);
        pk.s[2] = f2bf(v.z); pk.s[3] = f2bf(v.w);
        ((u32x2*)dst)[i] = pk.u;
    } else {
        // PE[l][ht] = dot(pos[l], Wp[ht]); PEr[h][w][t] = bf16(PE[2046-w][h*4+t])
        int o = (bx - CONV_BLOCKS) * 256 + threadIdx.x;
        if (o >= LPOS * 32) return;
        int l = o >> 5, ht = o & 31;
        const f32x4* pr = (const f32x4*)(pos + (size_t)l * 192);
        const f32x4* wr = (const f32x4*)(Wp + (size_t)ht * 192);
        float acc = 0.0f;
#pragma unroll 8
        for (int d = 0; d < 48; ++d) {
            f32x4 a = pr[d], w = wr[d];
            acc += a.x * w.x + a.y * w.y + a.z * w.z + a.w * w.w;
        }
        int h = ht >> 2, t = ht & 3, w = 2046 - l;
        PEr[((size_t)h * LPOS + w) * PD + t] = f2bf(acc);
    }
}

// ---------------------------------------------------------------------------
// Kernel 1: proj^T = W(544x512) @ X^T(512x8192) via MFMA.
// W o-tile staged in LDS (2 k-phases of 256), conflict-free padded rows.
// Block 256 (4 waves): tile 64 o x 64 m; wave wv: 16 m-rows, 4 o-subtiles.
// ---------------------------------------------------------------------------
#define WROW 264   // shorts per LDS W row (256 data + 8 pad): 528 B, 16B-aligned,
                   // row step 132 words -> +4 banks/row -> 2-way on b128 (free)
__global__ __launch_bounds__(256) void proj_kernel(
    const unsigned short* __restrict__ Xb, const unsigned short* __restrict__ Wb,
    const float* __restrict__ bias,
    unsigned short* __restrict__ Qb, unsigned short* __restrict__ Kb,
    unsigned short* __restrict__ Pb)
{
    __shared__ unsigned short wlds[64 * WROW];   // 33,792 B

    const int tid = threadIdx.x;
    const int wv = tid >> 6, lane = tid & 63;
    const int n16 = lane & 15, quad = lane >> 4;
    const int m0 = blockIdx.x * 64, o0 = blockIdx.y * 64;
    const int m = m0 + wv * 16 + n16;
    const unsigned short* xrow = Xb + (size_t)m * EMB;

    f32x4 acc[4] = {{0,0,0,0},{0,0,0,0},{0,0,0,0},{0,0,0,0}};

#pragma unroll
    for (int phase = 0; phase < 2; ++phase) {
        __syncthreads();   // previous phase fully consumed
#pragma unroll
        for (int u = 0; u < 8; ++u) {
            int idx = tid + 256 * u;          // 0..2047
            int r = idx >> 5, c = idx & 31;   // row, 16B chunk within 512B half-row
            int o = o0 + r; if (o > NPROJ - 1) o = NPROJ - 1;
            u32x4 v = *(const u32x4*)(Wb + (size_t)o * EMB + phase * 256 + c * 8);
            *(u32x4*)(wlds + r * WROW + c * 8) = v;
        }
        __syncthreads();
#pragma unroll
        for (int kk = 0; kk < 8; ++kk) {
            const int k0 = kk * 32;
            U4 bx; bx.u = *(const u32x4*)(xrow + phase * 256 + k0 + quad * 8);
#pragma unroll
            for (int ot = 0; ot < 4; ++ot) {
                U4 aw; aw.u = *(const u32x4*)(wlds + (ot * 16 + n16) * WROW + k0 + quad * 8);
                acc[ot] = __builtin_amdgcn_mfma_f32_16x16x32_bf16(aw.s, bx.s, acc[ot], 0, 0, 0);
            }
        }
    }

    const int s = m >> 3, b = m & 7;
#pragma unroll
    for (int ot = 0; ot < 4; ++ot) {
        int obase = o0 + ot * 16 + quad * 4;   // 4 consecutive o per lane
        if (obase >= NPROJ) continue;
        f32x4 bv = *(const f32x4*)(bias + obase);
        union { unsigned short sh[4]; u32x2 u; } pk;
        pk.sh[0] = f2bf(acc[ot].x + bv.x);
        pk.sh[1] = f2bf(acc[ot].y + bv.y);
        pk.sh[2] = f2bf(acc[ot].z + bv.z);
        pk.sh[3] = f2bf(acc[ot].w + bv.w);
        unsigned short* dst;
        if (obase < 256) {
            int h = obase >> 5, d = obase & 31;
            dst = Qb + (((size_t)(h * BATCH + b)) * S_LEN + s) * QD + d;
        } else if (obase < 512) {
            int o2 = obase - 256;
            int h = o2 >> 5, d = o2 & 31;
            dst = Kb + (((size_t)(h * BATCH + b)) * S_LEN + s) * QD + d;
        } else {
            int h = (obase - 512) >> 2;
            dst = Pb + (((size_t)(h * BATCH + b)) * S_LEN + s) * PD;
        }
        *(u32x2*)dst = pk.u;
    }
}

// ---------------------------------------------------------------------------
// Kernel 2: scores^T via MFMA + Toeplitz pos-fold + mask + softmax + write.
// Grid (S/16, H*B). Block 256 = 4 waves; wave wv covers j in [wv*256, +256).
// C^T tile: lane holds row i = i0 + (lane&15), cols j0+quad*4+{0..3}.
// PE window staged as PAIRS so each pos A-frag is one aligned ds_read_b128.
// launch_bounds (256,4): cap VGPR at 128 -> 4 blocks/CU (was 3) for latency
// hiding in the K-load t-loop (kernel is ~2.8x above its 43us store floor).
// ---------------------------------------------------------------------------
__global__ __launch_bounds__(256, 4) void attn_kernel(
    const unsigned short* __restrict__ Qb, const unsigned short* __restrict__ Kb,
    const unsigned short* __restrict__ Pb, const u32x2* __restrict__ PEr,
    const unsigned char* __restrict__ mask, float* __restrict__ out)
{
    __shared__ u32x4 pe_pair[1040];     // {PE4[w], PE4[w+1]} bf16, 16 B/slot
    __shared__ float madd[S_LEN];
    __shared__ float redm[4][16];
    __shared__ float reds[4][16];

    const int hb = blockIdx.y;
    const int h = hb >> 3, b = hb & 7;
    const int i0 = blockIdx.x * 16;
    const int tid = threadIdx.x;
    const int wv = tid >> 6, lane = tid & 63;
    const int n16 = lane & 15, quad = lane >> 4;

    // stage reversed-PE pair window: pe_pair[w] = {PE4r[i0+w], PE4r[i0+w+1]}
    // src[wl+1] is always inside the 128 KB PEr allocation (max byte offset
    // (7*2047+2047)*8+8 = 131072); slots >=1038 are never consumed, so the
    // unconditional load is safe and drops a cmp/select per iteration.
    const u32x2* src = PEr + (size_t)h * LPOS + i0;
    for (int wl = tid; wl < 1039; wl += 256) {
        u32x2 lo = src[wl];
        u32x2 hi = src[wl + 1];
        u32x4 v; v.x = lo.x; v.y = lo.y; v.z = hi.x; v.w = hi.y;
        pe_pair[wl] = v;
    }
    for (int j = tid; j < S_LEN; j += 256)
        madd[j] = mask[b * S_LEN + j] ? -INFINITY : 0.0f;

    // B1: Q fragment (row i0+n16, k = quad*8..+7)
    U4 b1; b1.u = *(const u32x4*)(Qb + ((size_t)hb * S_LEN + i0 + n16) * QD + quad * 8);
    // P row -> sparse B-frags for the two pos MFMAs
    u32x2 p4 = *(const u32x2*)(Pb + ((size_t)hb * S_LEN + i0 + n16) * PD);
    U4 b2, b3;
    b2.u.x = (n16 == 2 * quad)     ? p4.x : 0u;
    b2.u.y = (n16 == 2 * quad)     ? p4.y : 0u;
    b2.u.z = (n16 == 2 * quad + 1) ? p4.x : 0u;
    b2.u.w = (n16 == 2 * quad + 1) ? p4.y : 0u;
    b3.u.x = (n16 == 2 * quad + 8) ? p4.x : 0u;
    b3.u.y = (n16 == 2 * quad + 8) ? p4.y : 0u;
    b3.u.z = (n16 == 2 * quad + 9) ? p4.x : 0u;
    b3.u.w = (n16 == 2 * quad + 9) ? p4.y : 0u;

    __syncthreads();

    f32x4 sc[16];
    const unsigned short* kbase =
        Kb + (size_t)hb * S_LEN * QD + (size_t)(wv * 256 + n16) * QD + quad * 8;
    const int wbase = 1023 - wv * 256 - n16 + 2 * quad;

    // waves run this loop un-barriered; resident waves sit at different
    // phases (load vs MFMA vs store) -> setprio pays here (m191 regime)
    __builtin_amdgcn_s_setprio(1);
#pragma unroll
    for (int t = 0; t < 16; ++t) {
        U4 a1; a1.u = *(const u32x4*)(kbase + t * 16 * QD);
        U4 a2; a2.u = pe_pair[wbase - t * 16];
        U4 a3; a3.u = pe_pair[wbase - t * 16 + 8];
        f32x4 acc = {0.0f, 0.0f, 0.0f, 0.0f};
        acc = __builtin_amdgcn_mfma_f32_16x16x32_bf16(a3.s, b3.s, acc, 0, 0, 0);
        acc = __builtin_amdgcn_mfma_f32_16x16x32_bf16(a2.s, b2.s, acc, 0, 0, 0);
        acc = __builtin_amdgcn_mfma_f32_16x16x32_bf16(a1.s, b1.s, acc, 0, 0, 0);
        sc[t] = acc + *(const f32x4*)&madd[wv * 256 + t * 16 + quad * 4];
    }
    __builtin_amdgcn_s_setprio(0);

    // softmax over j for row i = i0 + n16 (lane holds only this row)
    float mx = -INFINITY;
#pragma unroll
    for (int t = 0; t < 16; ++t)
        mx = fmaxf(mx, fmaxf(fmaxf(sc[t].x, sc[t].y), fmaxf(sc[t].z, sc[t].w)));
    mx = fmaxf(mx, __shfl_xor(mx, 16));
    mx = fmaxf(mx, __shfl_xor(mx, 32));
    if (quad == 0) redm[wv][n16] = mx;
    __syncthreads();
    mx = fmaxf(fmaxf(redm[0][n16], redm[1][n16]),
               fmaxf(redm[2][n16], redm[3][n16]));

    float sum = 0.0f;
#pragma unroll
    for (int t = 0; t < 16; ++t) {
        sc[t].x = __expf(sc[t].x - mx);
        sc[t].y = __expf(sc[t].y - mx);
        sc[t].z = __expf(sc[t].z - mx);
        sc[t].w = __expf(sc[t].w - mx);
        sum += sc[t].x + sc[t].y + sc[t].z + sc[t].w;
    }
    sum += __shfl_xor(sum, 16);
    sum += __shfl_xor(sum, 32);
    if (quad == 0) reds[wv][n16] = sum;
    __syncthreads();
    const float tot = reds[0][n16] + reds[1][n16] + reds[2][n16] + reds[3][n16];
    const float inv = 1.0f / tot;

    float* orow = out + ((size_t)hb * S_LEN + i0 + n16) * S_LEN;
#pragma unroll
    for (int t = 0; t < 16; ++t) {
        const int j0 = wv * 256 + t * 16 + quad * 4;
        f32x4 o4 = sc[t] * inv;
        __builtin_nontemporal_store(o4, (f32x4*)(orow + j0));
    }
}

// ---------------------------------------------------------------------------
extern "C" void kernel_launch(void* const* d_in, const int* in_sizes, int n_in,
                              void* d_out, int out_size, void* d_ws, size_t ws_size,
                              hipStream_t stream) {
    (void)in_sizes; (void)n_in; (void)out_size; (void)ws_size;
    const float* x           = (const float*)d_in[0];
    const float* pos_emb     = (const float*)d_in[1];
    const unsigned char* msk = (const unsigned char*)d_in[2];
    const float* in_proj_w   = (const float*)d_in[3];
    const float* in_proj_b   = (const float*)d_in[4];
    const float* linear_posw = (const float*)d_in[5];
    float* out = (float*)d_out;

    char* p = (char*)d_ws;
    unsigned short* Qb  = (unsigned short*)p; p += (size_t)4 << 20;  // 4 MB
    unsigned short* Kb  = (unsigned short*)p; p += (size_t)4 << 20;  // 4 MB
    unsigned short* Pb  = (unsigned short*)p; p += 524288;           // 0.5 MB
    unsigned short* PEr = (unsigned short*)p; p += 131072;           // 128 KB
    unsigned short* Xb  = (unsigned short*)p; p += (size_t)8 << 20;  // 8 MB
    unsigned short* Wb  = (unsigned short*)p; p += 557056;           // ~0.53 MB

    prep_kernel<<<4624, 256, 0, stream>>>(x, in_proj_w, pos_emb, linear_posw, Xb, Wb, PEr);
    proj_kernel<<<dim3(128, 9), 256, 0, stream>>>(Xb, Wb, in_proj_b, Qb, Kb, Pb);
    attn_kernel<<<dim3(64, 64), 256, 0, stream>>>(Qb, Kb, Pb, (const u32x2*)PEr, msk, out);
}